// Round 9
// baseline (441.451 us; speedup 1.0000x reference)
//
#include <hip/hip_runtime.h>
#include <stdint.h>

typedef unsigned short u16;
typedef __attribute__((ext_vector_type(8))) short short8;
typedef __attribute__((ext_vector_type(4))) float f32x4;

#define SEQ    4096
#define NB     8
#define DMODEL 1024
#define MTOT   (NB*SEQ)   // 32768

static __device__ __forceinline__ float bf2f(u16 u){
  union { float f; uint32_t i; } v; v.i = ((uint32_t)u) << 16; return v.f;
}
static __device__ __forceinline__ u16 f2bf(float f){
  union { float f; uint32_t i; } v; v.f = f;
  uint32_t i = v.i + 0x7FFFu + ((v.i >> 16) & 1u);   // RTE
  return (u16)(i >> 16);
}

static __device__ __forceinline__ void stage16(const void* g, void* l){
  __builtin_amdgcn_global_load_lds(
      (const __attribute__((address_space(1))) void*)g,
      (__attribute__((address_space(3))) void*)l,
      16, 0, 0);
}

__global__ void cvt_f32_bf16(const float* __restrict__ s, u16* __restrict__ d, int n){
  int i = (blockIdx.x * 256 + threadIdx.x) * 8;
  if (i >= n) return;
  float4 a = *(const float4*)(s + i);
  float4 b = *(const float4*)(s + i + 4);
  union { u16 h[8]; short8 v; } o;
  o.h[0]=f2bf(a.x); o.h[1]=f2bf(a.y); o.h[2]=f2bf(a.z); o.h[3]=f2bf(a.w);
  o.h[4]=f2bf(b.x); o.h[5]=f2bf(b.y); o.h[6]=f2bf(b.z); o.h[7]=f2bf(b.w);
  *(short8*)(d + i) = o.v;
}

// 64x64 tile: in [R][C] f32 -> outN [R][C] bf16 (optional), outT [C][R] bf16
__global__ __launch_bounds__(256)
void cvt_tr(const float* __restrict__ in, u16* __restrict__ outN,
            u16* __restrict__ outT, int R, int C)
{
  __shared__ float t[64][65];
  const int tid = threadIdx.x;
  const int ntc = C >> 6;
  const int tr = blockIdx.x / ntc, tc = blockIdx.x % ntc;
  const int r0 = tr << 6, c0 = tc << 6;
  const int lrow = tid >> 4, lc4 = (tid & 15) << 2;
  #pragma unroll
  for (int p = 0; p < 4; p++){
    float4 v = *(const float4*)(in + (size_t)(r0 + p*16 + lrow) * C + c0 + lc4);
    t[p*16 + lrow][lc4+0] = v.x; t[p*16 + lrow][lc4+1] = v.y;
    t[p*16 + lrow][lc4+2] = v.z; t[p*16 + lrow][lc4+3] = v.w;
  }
  __syncthreads();
  const int wrow = tid >> 3, wc8 = (tid & 7) << 3;
  if (outN){
    #pragma unroll
    for (int p = 0; p < 2; p++){
      int r = p*32 + wrow;
      union { u16 h[8]; short8 v; } o;
      #pragma unroll
      for (int j = 0; j < 8; j++) o.h[j] = f2bf(t[r][wc8 + j]);
      *(short8*)(outN + (size_t)(r0 + r) * C + c0 + wc8) = o.v;
    }
  }
  #pragma unroll
  for (int p = 0; p < 2; p++){
    int c = p*32 + wrow;
    union { u16 h[8]; short8 v; } o;
    #pragma unroll
    for (int j = 0; j < 8; j++) o.h[j] = f2bf(t[wc8 + j][c]);
    *(short8*)(outT + (size_t)(c0 + c) * R + r0 + wc8) = o.v;
  }
}

// bo2[o] = bo[o] + sum_e Wo[o][e]*bv[e]
__global__ void bo2_kernel(const float* __restrict__ Wo, const float* __restrict__ bv,
                           const float* __restrict__ bo, float* __restrict__ bo2){
  int o = blockIdx.x * 4 + (threadIdx.x >> 6);
  int lane = threadIdx.x & 63;
  const float* row = Wo + (size_t)o * DMODEL;
  float s = 0.f;
  #pragma unroll
  for (int j = 0; j < 4; j++){
    float4 w = *(const float4*)(row + j*256 + lane*4);
    float4 b = *(const float4*)(bv  + j*256 + lane*4);
    s += w.x*b.x + w.y*b.y + w.z*b.z + w.w*b.w;
  }
  for (int off = 32; off; off >>= 1) s += __shfl_xor(s, off);
  if (lane == 0) bo2[o] = bo[o] + s;
}

// Ksum[b][d] = 1e-6 + sum_n Kt[d][b*4096+n]
__global__ void ksum_kernel(const u16* __restrict__ Kt, float* __restrict__ Ksum){
  int wid  = blockIdx.x * 4 + (threadIdx.x >> 6);
  int lane = threadIdx.x & 63;
  int d = wid & 1023, b = wid >> 10;
  const u16* row = Kt + (size_t)d * MTOT + (size_t)b * SEQ;
  float s = 0.f;
  #pragma unroll
  for (int j = 0; j < 8; j++){
    short8 v = *(const short8*)(row + j * 512 + lane * 8);
    #pragma unroll
    for (int t = 0; t < 8; t++) s += bf2f((u16)v[t]);
  }
  for (int off = 32; off; off >>= 1) s += __shfl_xor(s, off);
  if (lane == 0) Ksum[wid] = s + 1e-6f;
}

__global__ void z_kernel(const u16* __restrict__ Qb, const float* __restrict__ Ksum,
                         float* __restrict__ Z){
  int n    = blockIdx.x * 4 + (threadIdx.x >> 6);
  int lane = threadIdx.x & 63;
  const u16*   qrow = Qb + (size_t)n * DMODEL;
  const float* ks   = Ksum + (size_t)(n >> 12) * DMODEL;
  float s = 0.f;
  #pragma unroll
  for (int j = 0; j < 2; j++){
    int base = j * 512 + lane * 8;
    short8 q  = *(const short8*)(qrow + base);
    float4 k0 = *(const float4*)(ks + base);
    float4 k1 = *(const float4*)(ks + base + 4);
    s += bf2f((u16)q[0])*k0.x + bf2f((u16)q[1])*k0.y + bf2f((u16)q[2])*k0.z + bf2f((u16)q[3])*k0.w
       + bf2f((u16)q[4])*k1.x + bf2f((u16)q[5])*k1.y + bf2f((u16)q[6])*k1.z + bf2f((u16)q[7])*k1.w;
  }
  for (int off = 32; off; off >>= 1) s += __shfl_xor(s, off);
  if (lane == 0) Z[n] = s;
}

// ---------------- 128x128 kernel (W2 only) ----------------------------------
__global__ __launch_bounds__(256)
void gemm_bt(const u16* __restrict__ A, int ldA,
             const u16* __restrict__ BT, int ldBT, int Kdim,
             u16* __restrict__ Obf, int ldO)
{
  __shared__ u16 Al[128 * 32];
  __shared__ u16 Bl[128 * 32];
  const int tid  = threadIdx.x;
  const int lane = tid & 63;
  const int w    = tid >> 6;
  const int tcol = blockIdx.x;
  const int trow = blockIdx.y;

  const u16* Ap = A  + (size_t)trow * 128 * ldA;
  const u16* Bp = BT + (size_t)tcol * 128 * ldBT;

  f32x4 acc[4][4] = {};
  const int srow = (lane >> 2);
  const int scol = (lane & 3) * 8;

  for (int k0 = 0; k0 < Kdim; k0 += 32){
    #pragma unroll
    for (int i = 0; i < 2; i++){
      int r = w * 32 + i * 16 + srow;
      stage16(Ap + (size_t)r * ldA  + k0 + scol, (char*)Al + w * 2048 + i * 1024);
      stage16(Bp + (size_t)r * ldBT + k0 + scol, (char*)Bl + w * 2048 + i * 1024);
    }
    __syncthreads();
    const int mr = (w >> 1) * 64, nc = (w & 1) * 64;
    const int lr = lane & 15, lk = (lane >> 4) * 8;
    short8 av[4], bv[4];
    #pragma unroll
    for (int mi = 0; mi < 4; mi++) av[mi] = *(const short8*)&Al[(mr + mi*16 + lr)*32 + lk];
    #pragma unroll
    for (int nj = 0; nj < 4; nj++) bv[nj] = *(const short8*)&Bl[(nc + nj*16 + lr)*32 + lk];
    #pragma unroll
    for (int mi = 0; mi < 4; mi++)
      #pragma unroll
      for (int nj = 0; nj < 4; nj++)
        acc[mi][nj] = __builtin_amdgcn_mfma_f32_16x16x32_bf16(av[mi], bv[nj], acc[mi][nj], 0, 0, 0);
    __syncthreads();
  }

  const int mr = (w >> 1) * 64, nc = (w & 1) * 64;
  const int lr = lane & 15, lq = lane >> 4;
  #pragma unroll
  for (int mi = 0; mi < 4; mi++)
    #pragma unroll
    for (int r = 0; r < 4; r++){
      const size_t grow = (size_t)trow * 128 + mr + mi * 16 + lq * 4 + r;
      #pragma unroll
      for (int nj = 0; nj < 4; nj++){
        const size_t gcol = (size_t)tcol * 128 + nc + nj * 16 + lr;
        Obf[grow * ldO + gcol] = f2bf(acc[mi][nj][r]);
      }
    }
}

// stage one 128-row x 64-col half-tile (2 x global_load_lds per thread)
static __device__ __forceinline__ void stage_chunk(
    const u16* __restrict__ g, int ld, int k0, u16* smem, int baseU16, int tid){
  #pragma unroll
  for (int c = 0; c < 2; c++){
    int lin = c * 512 + tid;
    int row = lin >> 3;
    int slotL = (lin & 7) ^ (row & 7);
    stage16(g + (size_t)row * ld + k0 + slotL * 8,
            (char*)smem + baseU16 * 2 + (c * 8 + (tid >> 6)) * 1024);
  }
}

// ---------------- 256x256 relaxed counted-vmcnt kernel (K = NT*64) ----------
// (round-4 verified schedule: reads-all -> MFMA -> bar -> STAGE(t+2) -> vmcnt(8) -> bar)
// EPI: 0 = Q (bias[col]+elup1, bf16)         grid 512
//      1 = Kt (bias[row]+elup1, bf16)        grid 512
//      2 = final (v/Z[row]+bias[col], f32)   grid 512, BT=Gtall ldBT=8192
template<int EPI>
__global__ __launch_bounds__(512, 2)
void gemm8(const u16* __restrict__ A, int ldA,
           const u16* __restrict__ BT, int ldBT, int NT,
           const float* __restrict__ bias, const float* __restrict__ Zv,
           u16* __restrict__ Obf, float* __restrict__ Of32, int ldO)
{
  __shared__ u16 smem[65536];                 // 128 KiB
  const int tid  = threadIdx.x;
  const int lane = tid & 63;
  const int w    = tid >> 6;
  const int wm   = w >> 2, wn = w & 3;
  const int lr   = lane & 15, kq = lane >> 4;

  const int nwg  = gridDim.x;
  const int orig = blockIdx.x;
  const int work = (orig & 7) * (nwg >> 3) + (orig >> 3);
  int trow, tcol; size_t boff = 0;
  if (EPI == 1)      { trow = work & 3; tcol = work >> 2; }
  else               { tcol = work & 3; trow = work >> 2;
                       if (EPI == 2) boff = (size_t)(trow >> 4) * 1024; }
  const int tileM = trow * 256, tileN = tcol * 256;

  const u16* Ag = A + (size_t)tileM * ldA;
  const u16* Bg = BT + boff + (size_t)tileN * ldBT;

  f32x4 acc[8][4] = {};

#define STAGE(buf, k0) do { \
    stage_chunk(Ag,                    ldA,  (k0), smem, (buf) + 0,     tid); \
    stage_chunk(Ag + (size_t)128*ldA,  ldA,  (k0), smem, (buf) + 8192,  tid); \
    stage_chunk(Bg,                    ldBT, (k0), smem, (buf) + 16384, tid); \
    stage_chunk(Bg + (size_t)128*ldBT, ldBT, (k0), smem, (buf) + 24576, tid); \
  } while(0)

#define LDSA(MF, KC) (*(const short8*)(smem + cb + (wm*128 + (MF)*16 + lr)*64 + ((((KC)*4 + kq) ^ (lr & 7)) * 8)))
#define LDSB(NF, KC) (*(const short8*)(smem + cb + 16384 + (wn*64 + (NF)*16 + lr)*64 + ((((KC)*4 + kq) ^ (lr & 7)) * 8)))

  // prologue: tile0 -> buf0, tile1 -> buf1
  STAGE(0, 0);
  STAGE(32768, 64);
  asm volatile("s_waitcnt vmcnt(8)" ::: "memory");   // tile0 landed
  __builtin_amdgcn_sched_barrier(0);
  __builtin_amdgcn_s_barrier();

  for (int t = 0; t < NT; t++){
    const int cb = (t & 1) << 15;
    short8 af[4][2], ah[4][2], bf[4][2];
    #pragma unroll
    for (int i = 0; i < 4; i++){ af[i][0] = LDSA(i, 0);   af[i][1] = LDSA(i, 1); }
    #pragma unroll
    for (int i = 0; i < 4; i++){ bf[i][0] = LDSB(i, 0);   bf[i][1] = LDSB(i, 1); }
    __builtin_amdgcn_s_setprio(1);
    #pragma unroll
    for (int mi = 0; mi < 4; mi++)
      #pragma unroll
      for (int nj = 0; nj < 4; nj++)
        #pragma unroll
        for (int kc = 0; kc < 2; kc++)
          acc[mi][nj] = __builtin_amdgcn_mfma_f32_16x16x32_bf16(
              af[mi][kc], bf[nj][kc], acc[mi][nj], 0, 0, 0);
    __builtin_amdgcn_s_setprio(0);
    #pragma unroll
    for (int i = 0; i < 4; i++){ ah[i][0] = LDSA(4+i, 0); ah[i][1] = LDSA(4+i, 1); }
    __builtin_amdgcn_s_setprio(1);
    #pragma unroll
    for (int mi = 0; mi < 4; mi++)
      #pragma unroll
      for (int nj = 0; nj < 4; nj++)
        #pragma unroll
        for (int kc = 0; kc < 2; kc++)
          acc[4+mi][nj] = __builtin_amdgcn_mfma_f32_16x16x32_bf16(
              ah[mi][kc], bf[nj][kc], acc[4+mi][nj], 0, 0, 0);
    __builtin_amdgcn_s_setprio(0);

    __builtin_amdgcn_sched_barrier(0);
    __builtin_amdgcn_s_barrier();            // all waves done reading buf cb
    const int kNN = (t + 2 < NT ? t + 2 : NT - 1) * 64;
    STAGE(cb, kNN);                          // overwrite cb with tile t+2
    asm volatile("s_waitcnt vmcnt(8)" ::: "memory");   // tile t+1 landed
    __builtin_amdgcn_sched_barrier(0);
    __builtin_amdgcn_s_barrier();            // visible to all waves
  }

#undef STAGE
#undef LDSA
#undef LDSB

  // epilogue
  #pragma unroll
  for (int mf = 0; mf < 8; mf++){
    #pragma unroll
    for (int r = 0; r < 4; r++){
      const int grow = tileM + wm*128 + mf*16 + kq*4 + r;
      float rowB = 0.f, zin = 0.f;
      if (EPI == 1) rowB = bias[grow];
      if (EPI == 2) zin = 1.f / Zv[grow];
      #pragma unroll
      for (int nf = 0; nf < 4; nf++){
        const int gcol = tileN + wn*64 + nf*16 + lr;
        float v = acc[mf][nf][r];
        if (EPI == 0) { v += bias[gcol]; v = (v > 0.f) ? v + 1.f : __expf(v); }
        if (EPI == 1) { v += rowB;       v = (v > 0.f) ? v + 1.f : __expf(v); }
        if constexpr (EPI == 2) Of32[(size_t)grow * ldO + gcol] = v * zin + bias[gcol];
        else                    Obf [(size_t)grow * ldO + gcol] = f2bf(v);
      }
    }
  }
}

// ---------------- 128x256 relaxed kernel (T and Gt), grid 256 ---------------
// EPI: 3 = T  (batch per XCD, A=Kt BT=xT, NT=64)
//      4 = Gt (A=W2, BT=Tt flat 8192 rows, O=Gtall ld 8192, NT=16)
template<int EPI>
__global__ __launch_bounds__(512, 2)
void gemm8h(const u16* __restrict__ A, int ldA,
            const u16* __restrict__ BT, int ldBT, int NT,
            u16* __restrict__ Obf, int ldO)
{
  __shared__ u16 smem[49152];                 // 96 KiB: 2 bufs x (A 8192 + B 16384)
  const int tid  = threadIdx.x;
  const int lane = tid & 63;
  const int w    = tid >> 6;
  const int wm   = w >> 2, wn = w & 3;        // 2 x 4 waves, per-wave 64x64
  const int lr   = lane & 15, kq = lane >> 4;

  const int orig = blockIdx.x;
  const int work = (orig & 7) * 32 + (orig >> 3);
  int trow, tcol; size_t aoff = 0, boff = 0, ooff = 0;
  if (EPI == 3) { int zb = work >> 5, sub = work & 31;
                  trow = sub & 7; tcol = sub >> 3;
                  aoff = (size_t)zb * SEQ; boff = aoff; ooff = (size_t)zb << 20; }
  else          { trow = work & 7; tcol = work >> 3; }
  const int tileM = trow * 128, tileN = tcol * 256;

  const u16* Ag = A  + aoff + (size_t)tileM * ldA;
  const u16* Bg = BT + boff + (size_t)tileN * ldBT;

  f32x4 acc[4][4] = {};

#define STAGEH(buf, k0) do { \
    stage_chunk(Ag,                    ldA,  (k0), smem, (buf) + 0,     tid); \
    stage_chunk(Bg,                    ldBT, (k0), smem, (buf) + 8192,  tid); \
    stage_chunk(Bg + (size_t)128*ldBT, ldBT, (k0), smem, (buf) + 16384, tid); \
  } while(0)

#define LDSAH(MF, KC) (*(const short8*)(smem + cb + (wm*64 + (MF)*16 + lr)*64 + ((((KC)*4 + kq) ^ (lr & 7)) * 8)))
#define LDSBH(NF, KC) (*(const short8*)(smem + cb + 8192 + (wn*64 + (NF)*16 + lr)*64 + ((((KC)*4 + kq) ^ (lr & 7)) * 8)))

  STAGEH(0, 0);
  STAGEH(24576, 64);
  asm volatile("s_waitcnt vmcnt(6)" ::: "memory");
  __builtin_amdgcn_sched_barrier(0);
  __builtin_amdgcn_s_barrier();

  for (int t = 0; t < NT; t++){
    const int cb = (t & 1) * 24576;
    short8 af[4][2], bf[4][2];
    #pragma unroll
    for (int i = 0; i < 4; i++){ af[i][0] = LDSAH(i, 0); af[i][1] = LDSAH(i, 1); }
    #pragma unroll
    for (int i = 0; i < 4; i++){ bf[i][0] = LDSBH(i, 0); bf[i][1] = LDSBH(i, 1); }
    __builtin_amdgcn_s_setprio(1);
    #pragma unroll
    for (int mi = 0; mi < 4; mi++)
      #pragma unroll
      for (int nj = 0; nj < 4; nj++)
        #pragma unroll
        for (int kc = 0; kc < 2; kc++)
          acc[mi][nj] = __builtin_amdgcn_mfma_f32_16x16x32_bf16(
              af[mi][kc], bf[nj][kc], acc[mi][nj], 0, 0, 0);
    __builtin_amdgcn_s_setprio(0);
    __builtin_amdgcn_sched_barrier(0);
    __builtin_amdgcn_s_barrier();
    const int kNN = (t + 2 < NT ? t + 2 : NT - 1) * 64;
    STAGEH(cb, kNN);
    asm volatile("s_waitcnt vmcnt(6)" ::: "memory");
    __builtin_amdgcn_sched_barrier(0);
    __builtin_amdgcn_s_barrier();
  }
#undef STAGEH
#undef LDSAH
#undef LDSBH

  #pragma unroll
  for (int mf = 0; mf < 4; mf++){
    #pragma unroll
    for (int r = 0; r < 4; r++){
      const int grow = tileM + wm*64 + mf*16 + kq*4 + r;
      #pragma unroll
      for (int nf = 0; nf < 4; nf++){
        const int gcol = tileN + wn*64 + nf*16 + lr;
        Obf[ooff + (size_t)grow * ldO + gcol] = f2bf(acc[mf][nf][r]);
      }
    }
  }
}

extern "C" void kernel_launch(void* const* d_in, const int* in_sizes, int n_in,
                              void* d_out, int out_size, void* d_ws, size_t ws_size,
                              hipStream_t stream)
{
  const float* x  = (const float*)d_in[0];
  const float* Wq = (const float*)d_in[1];
  const float* bq = (const float*)d_in[2];
  const float* Wk = (const float*)d_in[3];
  const float* bk = (const float*)d_in[4];
  const float* Wv = (const float*)d_in[5];
  const float* bv = (const float*)d_in[6];
  const float* Wo = (const float*)d_in[7];
  const float* bo = (const float*)d_in[8];
  float* out = (float*)d_out;

  char* ws = (char*)d_ws;
  u16*   xb  = (u16*)(ws + 0);           // 64MB; dead after Kt GEMM
  u16*   Tt  = (u16*)(ws + 0);           // 16MB [8][1024 d][1024 dx] (aliases xb)
  u16*   Gt  = (u16*)(ws + 16777216);    // 16MB Gtall [1024 o][8192 (b,d)]
  u16*   xT  = (u16*)(ws + 67108864);    // 64MB [1024 dx][32768 n]
  u16*   Qb  = (u16*)(ws + 134217728);   // 64MB [32768][1024]
  u16*   Kt  = (u16*)(ws + 201326592);   // 64MB [1024 d][32768 n]
  u16*   Wqb = (u16*)(ws + 268435456);   // 2MB
  u16*   Wkb = (u16*)(ws + 270532608);   // 2MB
  u16*   Wob = (u16*)(ws + 272629760);   // 2MB
  u16*   WvT = (u16*)(ws + 274726912);   // 2MB [dx][e]
  u16*   W2b = (u16*)(ws + 276824064);   // 2MB [o][dx]
  float* Ks  = (float*)(ws + 278921216); // 32KB
  float* Zp  = (float*)(ws + 278953984); // 128KB
  float* bo2 = (float*)(ws + 279085056); // 4KB

  cvt_tr<<<8192, 256, 0, stream>>>(x, xb, xT, MTOT, DMODEL);
  cvt_f32_bf16<<<512, 256, 0, stream>>>(Wq, Wqb, DMODEL * DMODEL);
  cvt_f32_bf16<<<512, 256, 0, stream>>>(Wk, Wkb, DMODEL * DMODEL);
  cvt_f32_bf16<<<512, 256, 0, stream>>>(Wo, Wob, DMODEL * DMODEL);
  cvt_tr<<<256, 256, 0, stream>>>(Wv, (u16*)nullptr, WvT, DMODEL, DMODEL);
  bo2_kernel<<<256, 256, 0, stream>>>(Wo, bv, bo, bo2);
  // W2[o][dx] = sum_e Wo[o][e] WvT[dx][e]
  gemm_bt<<<dim3(8, 8, 1), dim3(256), 0, stream>>>(Wob, 1024, WvT, 1024, 1024,
                                                   W2b, 1024);

  // Q[n][d] = elup1(x Wq^T + bq)
  gemm8<0><<<512, 512, 0, stream>>>(xb, 1024, Wqb, 1024, 16, bq, nullptr,
                                    Qb, nullptr, 1024);
  // Kt[d][n] = elup1(Wk x^T + bk)
  gemm8<1><<<512, 512, 0, stream>>>(Wkb, 1024, xb, 1024, 16, bk, nullptr,
                                    Kt, nullptr, MTOT);
  // Ksum, Z
  ksum_kernel<<<2048, 256, 0, stream>>>(Kt, Ks);
  z_kernel<<<8192, 256, 0, stream>>>(Qb, Ks, Zp);
  // T_b[d][dx] = sum_n Kt[d][bn] xT[dx][bn]   (256 blocks, one batch per XCD)
  gemm8h<3><<<256, 512, 0, stream>>>(Kt, MTOT, xT, MTOT, 64, Tt, 1024);
  // Gtall[o][b*1024+d] = sum_dx W2[o][dx] Tt[(b,d)][dx]   (256 blocks)
  gemm8h<4><<<256, 512, 0, stream>>>(W2b, 1024, Tt, 1024, 16, Gt, 8192);
  // out[n][o] = (sum_d Q[n][d] Gtall[o][b*1024+d]) / Z[n] + bo2[o]
  gemm8<2><<<512, 512, 0, stream>>>(Qb, 1024, Gt, 8192, 16, bo2, Zp,
                                    nullptr, out, 1024);
}

// Round 10
// 428.749 us; speedup vs baseline: 1.0296x; 1.0296x over previous
//
#include <hip/hip_runtime.h>
#include <stdint.h>

typedef unsigned short u16;
typedef __attribute__((ext_vector_type(8))) short short8;
typedef __attribute__((ext_vector_type(4))) float f32x4;

#define SEQ    4096
#define NB     8
#define DMODEL 1024
#define MTOT   (NB*SEQ)   // 32768

static __device__ __forceinline__ float bf2f(u16 u){
  union { float f; uint32_t i; } v; v.i = ((uint32_t)u) << 16; return v.f;
}
static __device__ __forceinline__ u16 f2bf(float f){
  union { float f; uint32_t i; } v; v.f = f;
  uint32_t i = v.i + 0x7FFFu + ((v.i >> 16) & 1u);   // RTE
  return (u16)(i >> 16);
}

static __device__ __forceinline__ void stage16(const void* g, void* l){
  __builtin_amdgcn_global_load_lds(
      (const __attribute__((address_space(1))) void*)g,
      (__attribute__((address_space(3))) void*)l,
      16, 0, 0);
}

__global__ void cvt_f32_bf16(const float* __restrict__ s, u16* __restrict__ d, int n){
  int i = (blockIdx.x * 256 + threadIdx.x) * 8;
  if (i >= n) return;
  float4 a = *(const float4*)(s + i);
  float4 b = *(const float4*)(s + i + 4);
  union { u16 h[8]; short8 v; } o;
  o.h[0]=f2bf(a.x); o.h[1]=f2bf(a.y); o.h[2]=f2bf(a.z); o.h[3]=f2bf(a.w);
  o.h[4]=f2bf(b.x); o.h[5]=f2bf(b.y); o.h[6]=f2bf(b.z); o.h[7]=f2bf(b.w);
  *(short8*)(d + i) = o.v;
}

// 64x64 tile: in [R][C] f32 -> outN [R][C] bf16 (optional), outT [C][R] bf16
__global__ __launch_bounds__(256)
void cvt_tr(const float* __restrict__ in, u16* __restrict__ outN,
            u16* __restrict__ outT, int R, int C)
{
  __shared__ float t[64][65];
  const int tid = threadIdx.x;
  const int ntc = C >> 6;
  const int tr = blockIdx.x / ntc, tc = blockIdx.x % ntc;
  const int r0 = tr << 6, c0 = tc << 6;
  const int lrow = tid >> 4, lc4 = (tid & 15) << 2;
  #pragma unroll
  for (int p = 0; p < 4; p++){
    float4 v = *(const float4*)(in + (size_t)(r0 + p*16 + lrow) * C + c0 + lc4);
    t[p*16 + lrow][lc4+0] = v.x; t[p*16 + lrow][lc4+1] = v.y;
    t[p*16 + lrow][lc4+2] = v.z; t[p*16 + lrow][lc4+3] = v.w;
  }
  __syncthreads();
  const int wrow = tid >> 3, wc8 = (tid & 7) << 3;
  if (outN){
    #pragma unroll
    for (int p = 0; p < 2; p++){
      int r = p*32 + wrow;
      union { u16 h[8]; short8 v; } o;
      #pragma unroll
      for (int j = 0; j < 8; j++) o.h[j] = f2bf(t[r][wc8 + j]);
      *(short8*)(outN + (size_t)(r0 + r) * C + c0 + wc8) = o.v;
    }
  }
  #pragma unroll
  for (int p = 0; p < 2; p++){
    int c = p*32 + wrow;
    union { u16 h[8]; short8 v; } o;
    #pragma unroll
    for (int j = 0; j < 8; j++) o.h[j] = f2bf(t[wc8 + j][c]);
    *(short8*)(outT + (size_t)(c0 + c) * R + r0 + wc8) = o.v;
  }
}

// bo2[o] = bo[o] + sum_e Wo[o][e]*bv[e]
__global__ void bo2_kernel(const float* __restrict__ Wo, const float* __restrict__ bv,
                           const float* __restrict__ bo, float* __restrict__ bo2){
  int o = blockIdx.x * 4 + (threadIdx.x >> 6);
  int lane = threadIdx.x & 63;
  const float* row = Wo + (size_t)o * DMODEL;
  float s = 0.f;
  #pragma unroll
  for (int j = 0; j < 4; j++){
    float4 w = *(const float4*)(row + j*256 + lane*4);
    float4 b = *(const float4*)(bv  + j*256 + lane*4);
    s += w.x*b.x + w.y*b.y + w.z*b.z + w.w*b.w;
  }
  for (int off = 32; off; off >>= 1) s += __shfl_xor(s, off);
  if (lane == 0) bo2[o] = bo[o] + s;
}

// Ksum[b][d] = 1e-6 + sum_n Kt[d][b*4096+n]
__global__ void ksum_kernel(const u16* __restrict__ Kt, float* __restrict__ Ksum){
  int wid  = blockIdx.x * 4 + (threadIdx.x >> 6);
  int lane = threadIdx.x & 63;
  int d = wid & 1023, b = wid >> 10;
  const u16* row = Kt + (size_t)d * MTOT + (size_t)b * SEQ;
  float s = 0.f;
  #pragma unroll
  for (int j = 0; j < 8; j++){
    short8 v = *(const short8*)(row + j * 512 + lane * 8);
    #pragma unroll
    for (int t = 0; t < 8; t++) s += bf2f((u16)v[t]);
  }
  for (int off = 32; off; off >>= 1) s += __shfl_xor(s, off);
  if (lane == 0) Ksum[wid] = s + 1e-6f;
}

__global__ void z_kernel(const u16* __restrict__ Qb, const float* __restrict__ Ksum,
                         float* __restrict__ Z){
  int n    = blockIdx.x * 4 + (threadIdx.x >> 6);
  int lane = threadIdx.x & 63;
  const u16*   qrow = Qb + (size_t)n * DMODEL;
  const float* ks   = Ksum + (size_t)(n >> 12) * DMODEL;
  float s = 0.f;
  #pragma unroll
  for (int j = 0; j < 2; j++){
    int base = j * 512 + lane * 8;
    short8 q  = *(const short8*)(qrow + base);
    float4 k0 = *(const float4*)(ks + base);
    float4 k1 = *(const float4*)(ks + base + 4);
    s += bf2f((u16)q[0])*k0.x + bf2f((u16)q[1])*k0.y + bf2f((u16)q[2])*k0.z + bf2f((u16)q[3])*k0.w
       + bf2f((u16)q[4])*k1.x + bf2f((u16)q[5])*k1.y + bf2f((u16)q[6])*k1.z + bf2f((u16)q[7])*k1.w;
  }
  for (int off = 32; off; off >>= 1) s += __shfl_xor(s, off);
  if (lane == 0) Z[n] = s;
}

// ---------------- 128x128 kernel (W2 only) ----------------------------------
__global__ __launch_bounds__(256)
void gemm_bt(const u16* __restrict__ A, int ldA,
             const u16* __restrict__ BT, int ldBT, int Kdim,
             u16* __restrict__ Obf, int ldO)
{
  __shared__ u16 Al[128 * 32];
  __shared__ u16 Bl[128 * 32];
  const int tid  = threadIdx.x;
  const int lane = tid & 63;
  const int w    = tid >> 6;
  const int tcol = blockIdx.x;
  const int trow = blockIdx.y;

  const u16* Ap = A  + (size_t)trow * 128 * ldA;
  const u16* Bp = BT + (size_t)tcol * 128 * ldBT;

  f32x4 acc[4][4] = {};
  const int srow = (lane >> 2);
  const int scol = (lane & 3) * 8;

  for (int k0 = 0; k0 < Kdim; k0 += 32){
    #pragma unroll
    for (int i = 0; i < 2; i++){
      int r = w * 32 + i * 16 + srow;
      stage16(Ap + (size_t)r * ldA  + k0 + scol, (char*)Al + w * 2048 + i * 1024);
      stage16(Bp + (size_t)r * ldBT + k0 + scol, (char*)Bl + w * 2048 + i * 1024);
    }
    __syncthreads();
    const int mr = (w >> 1) * 64, nc = (w & 1) * 64;
    const int lr = lane & 15, lk = (lane >> 4) * 8;
    short8 av[4], bv[4];
    #pragma unroll
    for (int mi = 0; mi < 4; mi++) av[mi] = *(const short8*)&Al[(mr + mi*16 + lr)*32 + lk];
    #pragma unroll
    for (int nj = 0; nj < 4; nj++) bv[nj] = *(const short8*)&Bl[(nc + nj*16 + lr)*32 + lk];
    #pragma unroll
    for (int mi = 0; mi < 4; mi++)
      #pragma unroll
      for (int nj = 0; nj < 4; nj++)
        acc[mi][nj] = __builtin_amdgcn_mfma_f32_16x16x32_bf16(av[mi], bv[nj], acc[mi][nj], 0, 0, 0);
    __syncthreads();
  }

  const int mr = (w >> 1) * 64, nc = (w & 1) * 64;
  const int lr = lane & 15, lq = lane >> 4;
  #pragma unroll
  for (int mi = 0; mi < 4; mi++)
    #pragma unroll
    for (int r = 0; r < 4; r++){
      const size_t grow = (size_t)trow * 128 + mr + mi * 16 + lq * 4 + r;
      #pragma unroll
      for (int nj = 0; nj < 4; nj++){
        const size_t gcol = (size_t)tcol * 128 + nc + nj * 16 + lr;
        Obf[grow * ldO + gcol] = f2bf(acc[mi][nj][r]);
      }
    }
}

// stage one 128-row x 64-col half-tile (2 x global_load_lds per thread)
static __device__ __forceinline__ void stage_chunk(
    const u16* __restrict__ g, int ld, int k0, u16* smem, int baseU16, int tid){
  #pragma unroll
  for (int c = 0; c < 2; c++){
    int lin = c * 512 + tid;
    int row = lin >> 3;
    int slotL = (lin & 7) ^ (row & 7);
    stage16(g + (size_t)row * ld + k0 + slotL * 8,
            (char*)smem + baseU16 * 2 + (c * 8 + (tid >> 6)) * 1024);
  }
}

// ---------------- 256x256 4-phase (m201-style) kernel (K = NT*64) -----------
// Per-wave C = 128x64, quadrant phases (h,g): (0,0)->(0,1)->(1,1)->(1,0).
// Half-tile read-completion points (proven by lgkmcnt(0)+closing barrier):
//   B0,B1 dead after ph1; A0,A1 dead after ph2.  Stage t+2 into the dead
//   regions of the CURRENT buffer: B0 at ph2; B1,A0,A1 at ph3.
// Ledger: one vmcnt(8) per tile (t+2's 8 loads newest => t+1 landed).
// EPI: 0 = Q (bias[col]+elup1, bf16)         grid 512
//      1 = Kt (bias[row]+elup1, bf16)        grid 512
//      2 = final (v/Z[row]+bias[col], f32)   grid 512, BT=Gtall ldBT=8192
template<int EPI>
__global__ __launch_bounds__(512, 2)
void gemm8(const u16* __restrict__ A, int ldA,
           const u16* __restrict__ BT, int ldBT, int NT,
           const float* __restrict__ bias, const float* __restrict__ Zv,
           u16* __restrict__ Obf, float* __restrict__ Of32, int ldO)
{
  __shared__ u16 smem[65536];                 // 128 KiB
  const int tid  = threadIdx.x;
  const int lane = tid & 63;
  const int w    = tid >> 6;
  const int wm   = w >> 2, wn = w & 3;
  const int lr   = lane & 15, kq = lane >> 4;

  const int nwg  = gridDim.x;
  const int orig = blockIdx.x;
  const int work = (orig & 7) * (nwg >> 3) + (orig >> 3);
  int trow, tcol; size_t boff = 0;
  if (EPI == 1)      { trow = work & 3; tcol = work >> 2; }
  else               { tcol = work & 3; trow = work >> 2;
                       if (EPI == 2) boff = (size_t)(trow >> 4) * 1024; }
  const int tileM = trow * 256, tileN = tcol * 256;

  const u16* Ag = A + (size_t)tileM * ldA;
  const u16* Bg = BT + boff + (size_t)tileN * ldBT;

  f32x4 acc[8][4] = {};

#define STAGE(buf, k0) do { \
    stage_chunk(Ag,                    ldA,  (k0), smem, (buf) + 0,     tid); \
    stage_chunk(Ag + (size_t)128*ldA,  ldA,  (k0), smem, (buf) + 8192,  tid); \
    stage_chunk(Bg,                    ldBT, (k0), smem, (buf) + 16384, tid); \
    stage_chunk(Bg + (size_t)128*ldBT, ldBT, (k0), smem, (buf) + 24576, tid); \
  } while(0)

#define LDSA(MF, KC) (*(const short8*)(smem + cb + (wm*128 + (MF)*16 + lr)*64 + ((((KC)*4 + kq) ^ (lr & 7)) * 8)))
#define LDSB(NF, KC) (*(const short8*)(smem + cb + 16384 + (wn*64 + (NF)*16 + lr)*64 + ((((KC)*4 + kq) ^ (lr & 7)) * 8)))

#define QUAD(M0, N0, AV, BV) do { \
  __builtin_amdgcn_s_setprio(1); \
  _Pragma("unroll") for (int mi = 0; mi < 4; mi++) \
    _Pragma("unroll") for (int ni = 0; ni < 2; ni++) \
      _Pragma("unroll") for (int kc = 0; kc < 2; kc++) \
        acc[(M0)+mi][(N0)+ni] = __builtin_amdgcn_mfma_f32_16x16x32_bf16( \
            AV[mi][kc], BV[ni][kc], acc[(M0)+mi][(N0)+ni], 0, 0, 0); \
  __builtin_amdgcn_s_setprio(0); \
} while(0)

  // prologue: tile0 -> buf0, tile1 -> buf1
  STAGE(0, 0);
  STAGE(32768, 64);
  asm volatile("s_waitcnt vmcnt(8)" ::: "memory");   // tile0 landed
  __builtin_amdgcn_s_barrier();

  for (int t = 0; t < NT; t++){
    const int cb  = (t & 1) << 15;
    const int kNN = (t + 2 < NT ? t + 2 : NT - 1) * 64;
    short8 a0[4][2], a1[4][2], bl[2][2], bh[2][2];

    // ph0: quadrant (h0,g0)
    #pragma unroll
    for (int i = 0; i < 4; i++){ a0[i][0] = LDSA(i, 0);   a0[i][1] = LDSA(i, 1); }
    #pragma unroll
    for (int i = 0; i < 2; i++){ bl[i][0] = LDSB(i, 0);   bl[i][1] = LDSB(i, 1); }
    __builtin_amdgcn_s_barrier();
    asm volatile("s_waitcnt lgkmcnt(0)" ::: "memory");
    QUAD(0, 0, a0, bl);
    __builtin_amdgcn_s_barrier();

    // ph1: quadrant (h0,g1)
    #pragma unroll
    for (int i = 0; i < 2; i++){ bh[i][0] = LDSB(2+i, 0); bh[i][1] = LDSB(2+i, 1); }
    __builtin_amdgcn_s_barrier();
    asm volatile("s_waitcnt lgkmcnt(0)" ::: "memory");
    QUAD(0, 2, a0, bh);
    __builtin_amdgcn_s_barrier();
    // B0,B1 of tile t fully consumed by all waves here.

    // ph2: quadrant (h1,g1); stage B0(t+2) into dead B0 region of cb
    #pragma unroll
    for (int i = 0; i < 4; i++){ a1[i][0] = LDSA(4+i, 0); a1[i][1] = LDSA(4+i, 1); }
    stage_chunk(Bg, ldBT, kNN, smem, cb + 16384, tid);
    __builtin_amdgcn_s_barrier();
    asm volatile("s_waitcnt lgkmcnt(0)" ::: "memory");
    QUAD(4, 2, a1, bh);
    __builtin_amdgcn_s_barrier();
    // A0,A1 of tile t fully consumed by all waves here.

    // ph3: quadrant (h1,g0); stage B1,A0,A1(t+2); counted wait for tile t+1
    stage_chunk(Bg + (size_t)128*ldBT, ldBT, kNN, smem, cb + 24576, tid);
    stage_chunk(Ag,                    ldA,  kNN, smem, cb + 0,     tid);
    stage_chunk(Ag + (size_t)128*ldA,  ldA,  kNN, smem, cb + 8192,  tid);
    QUAD(4, 0, a1, bl);
    asm volatile("s_waitcnt vmcnt(8)" ::: "memory");   // t+1 landed (t+2 = newest 8)
    __builtin_amdgcn_s_barrier();
  }

#undef STAGE
#undef LDSA
#undef LDSB
#undef QUAD

  // epilogue
  #pragma unroll
  for (int mf = 0; mf < 8; mf++){
    #pragma unroll
    for (int r = 0; r < 4; r++){
      const int grow = tileM + wm*128 + mf*16 + kq*4 + r;
      float rowB = 0.f, zin = 0.f;
      if (EPI == 1) rowB = bias[grow];
      if (EPI == 2) zin = 1.f / Zv[grow];
      #pragma unroll
      for (int nf = 0; nf < 4; nf++){
        const int gcol = tileN + wn*64 + nf*16 + lr;
        float v = acc[mf][nf][r];
        if (EPI == 0) { v += bias[gcol]; v = (v > 0.f) ? v + 1.f : __expf(v); }
        if (EPI == 1) { v += rowB;       v = (v > 0.f) ? v + 1.f : __expf(v); }
        if constexpr (EPI == 2) Of32[(size_t)grow * ldO + gcol] = v * zin + bias[gcol];
        else                    Obf [(size_t)grow * ldO + gcol] = f2bf(v);
      }
    }
  }
}

// ---------------- 128x256 relaxed kernel (T and Gt), grid 256 ---------------
// EPI: 3 = T  (batch per XCD, A=Kt BT=xT, NT=64)
//      4 = Gt (A=W2, BT=Tt flat 8192 rows, O=Gtall ld 8192, NT=16)
template<int EPI>
__global__ __launch_bounds__(512, 2)
void gemm8h(const u16* __restrict__ A, int ldA,
            const u16* __restrict__ BT, int ldBT, int NT,
            u16* __restrict__ Obf, int ldO)
{
  __shared__ u16 smem[49152];                 // 96 KiB: 2 bufs x (A 8192 + B 16384)
  const int tid  = threadIdx.x;
  const int lane = tid & 63;
  const int w    = tid >> 6;
  const int wm   = w >> 2, wn = w & 3;        // 2 x 4 waves, per-wave 64x64
  const int lr   = lane & 15, kq = lane >> 4;

  const int orig = blockIdx.x;
  const int work = (orig & 7) * 32 + (orig >> 3);
  int trow, tcol; size_t aoff = 0, boff = 0, ooff = 0;
  if (EPI == 3) { int zb = work >> 5, sub = work & 31;
                  trow = sub & 7; tcol = sub >> 3;
                  aoff = (size_t)zb * SEQ; boff = aoff; ooff = (size_t)zb << 20; }
  else          { trow = work & 7; tcol = work >> 3; }
  const int tileM = trow * 128, tileN = tcol * 256;

  const u16* Ag = A  + aoff + (size_t)tileM * ldA;
  const u16* Bg = BT + boff + (size_t)tileN * ldBT;

  f32x4 acc[4][4] = {};

#define STAGEH(buf, k0) do { \
    stage_chunk(Ag,                    ldA,  (k0), smem, (buf) + 0,     tid); \
    stage_chunk(Bg,                    ldBT, (k0), smem, (buf) + 8192,  tid); \
    stage_chunk(Bg + (size_t)128*ldBT, ldBT, (k0), smem, (buf) + 16384, tid); \
  } while(0)

#define LDSAH(MF, KC) (*(const short8*)(smem + cb + (wm*64 + (MF)*16 + lr)*64 + ((((KC)*4 + kq) ^ (lr & 7)) * 8)))
#define LDSBH(NF, KC) (*(const short8*)(smem + cb + 8192 + (wn*64 + (NF)*16 + lr)*64 + ((((KC)*4 + kq) ^ (lr & 7)) * 8)))

  STAGEH(0, 0);
  STAGEH(24576, 64);
  asm volatile("s_waitcnt vmcnt(6)" ::: "memory");
  __builtin_amdgcn_sched_barrier(0);
  __builtin_amdgcn_s_barrier();

  for (int t = 0; t < NT; t++){
    const int cb = (t & 1) * 24576;
    short8 af[4][2], bf[4][2];
    #pragma unroll
    for (int i = 0; i < 4; i++){ af[i][0] = LDSAH(i, 0); af[i][1] = LDSAH(i, 1); }
    #pragma unroll
    for (int i = 0; i < 4; i++){ bf[i][0] = LDSBH(i, 0); bf[i][1] = LDSBH(i, 1); }
    __builtin_amdgcn_s_setprio(1);
    #pragma unroll
    for (int mi = 0; mi < 4; mi++)
      #pragma unroll
      for (int nj = 0; nj < 4; nj++)
        #pragma unroll
        for (int kc = 0; kc < 2; kc++)
          acc[mi][nj] = __builtin_amdgcn_mfma_f32_16x16x32_bf16(
              af[mi][kc], bf[nj][kc], acc[mi][nj], 0, 0, 0);
    __builtin_amdgcn_s_setprio(0);
    __builtin_amdgcn_sched_barrier(0);
    __builtin_amdgcn_s_barrier();
    const int kNN = (t + 2 < NT ? t + 2 : NT - 1) * 64;
    STAGEH(cb, kNN);
    asm volatile("s_waitcnt vmcnt(6)" ::: "memory");
    __builtin_amdgcn_sched_barrier(0);
    __builtin_amdgcn_s_barrier();
  }
#undef STAGEH
#undef LDSAH
#undef LDSBH

  #pragma unroll
  for (int mf = 0; mf < 4; mf++){
    #pragma unroll
    for (int r = 0; r < 4; r++){
      const int grow = tileM + wm*64 + mf*16 + kq*4 + r;
      #pragma unroll
      for (int nf = 0; nf < 4; nf++){
        const int gcol = tileN + wn*64 + nf*16 + lr;
        Obf[ooff + (size_t)grow * ldO + gcol] = f2bf(acc[mf][nf][r]);
      }
    }
  }
}

extern "C" void kernel_launch(void* const* d_in, const int* in_sizes, int n_in,
                              void* d_out, int out_size, void* d_ws, size_t ws_size,
                              hipStream_t stream)
{
  const float* x  = (const float*)d_in[0];
  const float* Wq = (const float*)d_in[1];
  const float* bq = (const float*)d_in[2];
  const float* Wk = (const float*)d_in[3];
  const float* bk = (const float*)d_in[4];
  const float* Wv = (const float*)d_in[5];
  const float* bv = (const float*)d_in[6];
  const float* Wo = (const float*)d_in[7];
  const float* bo = (const float*)d_in[8];
  float* out = (float*)d_out;

  char* ws = (char*)d_ws;
  u16*   xb  = (u16*)(ws + 0);           // 64MB; dead after Kt GEMM
  u16*   Tt  = (u16*)(ws + 0);           // 16MB [8][1024 d][1024 dx] (aliases xb)
  u16*   Gt  = (u16*)(ws + 16777216);    // 16MB Gtall [1024 o][8192 (b,d)]
  u16*   xT  = (u16*)(ws + 67108864);    // 64MB [1024 dx][32768 n]
  u16*   Qb  = (u16*)(ws + 134217728);   // 64MB [32768][1024]
  u16*   Kt  = (u16*)(ws + 201326592);   // 64MB [1024 d][32768 n]
  u16*   Wqb = (u16*)(ws + 268435456);   // 2MB
  u16*   Wkb = (u16*)(ws + 270532608);   // 2MB
  u16*   Wob = (u16*)(ws + 272629760);   // 2MB
  u16*   WvT = (u16*)(ws + 274726912);   // 2MB [dx][e]
  u16*   W2b = (u16*)(ws + 276824064);   // 2MB [o][dx]
  float* Ks  = (float*)(ws + 278921216); // 32KB
  float* Zp  = (float*)(ws + 278953984); // 128KB
  float* bo2 = (float*)(ws + 279085056); // 4KB

  cvt_tr<<<8192, 256, 0, stream>>>(x, xb, xT, MTOT, DMODEL);
  cvt_f32_bf16<<<512, 256, 0, stream>>>(Wq, Wqb, DMODEL * DMODEL);
  cvt_f32_bf16<<<512, 256, 0, stream>>>(Wk, Wkb, DMODEL * DMODEL);
  cvt_f32_bf16<<<512, 256, 0, stream>>>(Wo, Wob, DMODEL * DMODEL);
  cvt_tr<<<256, 256, 0, stream>>>(Wv, (u16*)nullptr, WvT, DMODEL, DMODEL);
  bo2_kernel<<<256, 256, 0, stream>>>(Wo, bv, bo, bo2);
  // W2[o][dx] = sum_e Wo[o][e] WvT[dx][e]
  gemm_bt<<<dim3(8, 8, 1), dim3(256), 0, stream>>>(Wob, 1024, WvT, 1024, 1024,
                                                   W2b, 1024);

  // Q[n][d] = elup1(x Wq^T + bq)
  gemm8<0><<<512, 512, 0, stream>>>(xb, 1024, Wqb, 1024, 16, bq, nullptr,
                                    Qb, nullptr, 1024);
  // Kt[d][n] = elup1(Wk x^T + bk)
  gemm8<1><<<512, 512, 0, stream>>>(Wkb, 1024, xb, 1024, 16, bk, nullptr,
                                    Kt, nullptr, MTOT);
  // Ksum, Z
  ksum_kernel<<<2048, 256, 0, stream>>>(Kt, Ks);
  z_kernel<<<8192, 256, 0, stream>>>(Qb, Ks, Zp);
  // T_b[d][dx] = sum_n Kt[d][bn] xT[dx][bn]   (256 blocks, one batch per XCD)
  gemm8h<3><<<256, 512, 0, stream>>>(Kt, MTOT, xT, MTOT, 64, Tt, 1024);
  // Gtall[o][b*1024+d] = sum_dx W2[o][dx] Tt[(b,d)][dx]   (256 blocks)
  gemm8h<4><<<256, 512, 0, stream>>>(W2b, 1024, Tt, 1024, 16, Gt, 8192);
  // out[n][o] = (sum_d Q[n][d] Gtall[o][b*1024+d]) / Z[n] + bo2[o]
  gemm8<2><<<512, 512, 0, stream>>>(Qb, 1024, Gt, 8192, 16, bo2, Zp,
                                    nullptr, out, 1024);
}